// Round 3
// baseline (23.287 us; speedup 1.0000x reference)
//
#include <hip/hip_runtime.h>
#include <math.h>

// Problem constants (match reference)
static constexpr int Bn = 8;
static constexpr int Nn = 16;
static constexpr int Mn = 4;
static constexpr int Cn = 2;
static constexpr int HWn = 256 * 256;   // 65536
static constexpr int SEGS = 64;         // segments per b
static constexpr int SEGLEN = HWn / SEGS; // 1024
#define GAMMA_F 0.5f
#define MASS_F 0.25f
#define EPS_F 1e-8f

// Workspace layout (bytes):
//   inter_part [B][N][M][SEGS] f32 : 131072 @ 0
//   ssum_part  [B][N][SEGS]    f32 :  32768 @ 131072
//   gsum_part  [B][M][SEGS]    f32 :   8192 @ 163840

// One block per (b, segment of 1024 elems). Wave w owns n = 4w..4w+3.
// gt is read ONCE from HBM; masks converted to float 0/1 and reused via FMA.
__global__ __launch_bounds__(256) void inter2_kernel(
    const float* __restrict__ sample, const int* __restrict__ gt,
    float* __restrict__ inter_part, float* __restrict__ ssum_part,
    float* __restrict__ gsum_part) {
  int seg = blockIdx.x & (SEGS - 1);
  int b = blockIdx.x >> 6;
  int tid = threadIdx.x;
  int w = tid >> 6;
  int lane = tid & 63;
  size_t segoff = (size_t)seg * SEGLEN;

  const int* gtb = gt + ((size_t)b * Mn) * HWn + segoff;
  // channel-1 plane of sample for n: sb + n*(Cn*HWn)
  const float* sb = sample + (size_t)b * Nn * Cn * HWn + HWn + segoff;

  float ss[4] = {0.f, 0.f, 0.f, 0.f};
  float im[4][4] = {};
  float cnt[4] = {0.f, 0.f, 0.f, 0.f};

#pragma unroll
  for (int q = 0; q < 4; ++q) {
    int idx = q * 64 + lane;
    int4 g0 = reinterpret_cast<const int4*>(gtb + 0 * HWn)[idx];
    int4 g1 = reinterpret_cast<const int4*>(gtb + 1 * HWn)[idx];
    int4 g2 = reinterpret_cast<const int4*>(gtb + 2 * HWn)[idx];
    int4 g3 = reinterpret_cast<const int4*>(gtb + 3 * HWn)[idx];
    float mf[4][4];  // [e][m], all indices compile-time (unrolled)
    {
      int a0[4] = {g0.x, g0.y, g0.z, g0.w};
      int a1[4] = {g1.x, g1.y, g1.z, g1.w};
      int a2[4] = {g2.x, g2.y, g2.z, g2.w};
      int a3[4] = {g3.x, g3.y, g3.z, g3.w};
#pragma unroll
      for (int e = 0; e < 4; ++e) {
        mf[e][0] = (a0[e] == 1) ? 1.f : 0.f;
        mf[e][1] = (a1[e] == 1) ? 1.f : 0.f;
        mf[e][2] = (a2[e] == 1) ? 1.f : 0.f;
        mf[e][3] = (a3[e] == 1) ? 1.f : 0.f;
      }
    }
#pragma unroll
    for (int m = 0; m < 4; ++m)
      cnt[m] += (mf[0][m] + mf[1][m]) + (mf[2][m] + mf[3][m]);
#pragma unroll
    for (int nn = 0; nn < 4; ++nn) {
      const float* spn = sb + (size_t)(w * 4 + nn) * (Cn * HWn);
      float4 x = reinterpret_cast<const float4*>(spn)[idx];
      float xs[4] = {x.x, x.y, x.z, x.w};
#pragma unroll
      for (int e = 0; e < 4; ++e) {
        float v = xs[e];
        ss[nn] += v;
#pragma unroll
        for (int m = 0; m < 4; ++m) im[nn][m] = fmaf(v, mf[e][m], im[nn][m]);
      }
    }
  }

  // Stage per-wave lane partials; rows padded to 68 floats (272 B, 16B-aligned).
  __shared__ __align__(16) float red[4][20][68];
  __shared__ __align__(16) float redc[4][68];
#pragma unroll
  for (int nn = 0; nn < 4; ++nn) {
    red[w][nn * 5 + 0][lane] = ss[nn];
#pragma unroll
    for (int m = 0; m < 4; ++m) red[w][nn * 5 + 1 + m][lane] = im[nn][m];
  }
  if (w == 0) {
#pragma unroll
    for (int m = 0; m < 4; ++m) redc[m][lane] = cnt[m];
  }
  __syncthreads();

  if (tid < 80) {
    int rw = tid / 20, v = tid % 20;
    const float4* row = reinterpret_cast<const float4*>(&red[rw][v][0]);
    float4 a4 = row[0];
#pragma unroll
    for (int j = 1; j < 16; ++j) {
      float4 t = row[j];
      a4.x += t.x; a4.y += t.y; a4.z += t.z; a4.w += t.w;
    }
    float s = (a4.x + a4.y) + (a4.z + a4.w);
    int n = rw * 4 + v / 5;
    int k = v % 5;
    int bn = b * Nn + n;
    if (k == 0)
      ssum_part[(size_t)bn * SEGS + seg] = s;
    else
      inter_part[((size_t)bn * Mn + (k - 1)) * SEGS + seg] = s;
  } else if (tid < 84) {
    int m = tid - 80;
    const float4* row = reinterpret_cast<const float4*>(&redc[m][0]);
    float4 a4 = row[0];
#pragma unroll
    for (int j = 1; j < 16; ++j) {
      float4 t = row[j];
      a4.x += t.x; a4.y += t.y; a4.z += t.z; a4.w += t.w;
    }
    float s = (a4.x + a4.y) + (a4.z + a4.w);
    gsum_part[((size_t)b * Mn + m) * SEGS + seg] = s;
  }
}

// Coupling + losses, register/shuffle based: one lane per (b,n) row.
__global__ __launch_bounds__(256) void finish_kernel(
    const float* __restrict__ inter_part, const float* __restrict__ ssum_part,
    const float* __restrict__ gsum_part,
    const float* __restrict__ prob, const float* __restrict__ prob_gt,
    float* __restrict__ out) {
  __shared__ float s_cost[Bn * Nn * Mn];   // [b][n][m]
  __shared__ float s_ssum[Bn * Nn];
  __shared__ float s_gsum[Bn * Mn];
  __shared__ float s_red[8];
  int tid = threadIdx.x;

  // phase 1a: sample row sums / gt sums (64-seg float4 reductions)
  if (tid < Bn * Nn) {
    const float4* row = reinterpret_cast<const float4*>(&ssum_part[(size_t)tid * SEGS]);
    float4 a4 = row[0];
#pragma unroll
    for (int j = 1; j < 16; ++j) {
      float4 t = row[j];
      a4.x += t.x; a4.y += t.y; a4.z += t.z; a4.w += t.w;
    }
    s_ssum[tid] = (a4.x + a4.y) + (a4.z + a4.w);
  } else if (tid < 128 + Bn * Mn) {
    int idx = tid - 128;
    const float4* row = reinterpret_cast<const float4*>(&gsum_part[(size_t)idx * SEGS]);
    float4 a4 = row[0];
#pragma unroll
    for (int j = 1; j < 16; ++j) {
      float4 t = row[j];
      a4.x += t.x; a4.y += t.y; a4.z += t.z; a4.w += t.w;
    }
    s_gsum[idx] = (a4.x + a4.y) + (a4.z + a4.w);
  }
  __syncthreads();

  // phase 1b: cost
  for (int idx = tid; idx < Bn * Nn * Mn; idx += 256) {
    int m = idx & 3;
    int bn = idx >> 2;
    int b = bn >> 4;
    const float4* row = reinterpret_cast<const float4*>(&inter_part[(size_t)idx * SEGS]);
    float4 a4 = row[0];
#pragma unroll
    for (int j = 1; j < 16; ++j) {
      float4 t = row[j];
      a4.x += t.x; a4.y += t.y; a4.z += t.z; a4.w += t.w;
    }
    float inter = (a4.x + a4.y) + (a4.z + a4.w);
    float uni = s_ssum[bn] + s_gsum[(b << 2) + m] - inter;
    s_cost[idx] = 1.0f - (inter + 1.0f) / (uni + 1.0f);
  }
  __syncthreads();

  // phase 2: coupling, lane per (b,n)
  float seg_part = 0.f, kl_part = 0.f;
  if (tid < Bn * Nn) {
    int b = tid >> 4;
    int n = tid & 15;
    int base = (tid & 63) & ~15;

    float4 cv = *reinterpret_cast<const float4*>(&s_cost[tid * Mn]);
    float cc0 = cv.x, cc1 = cv.y, cc2 = cv.z, cc3 = cv.w;
    float pg0 = prob_gt[b * Mn + 0], pg1 = prob_gt[b * Mn + 1];
    float pg2 = prob_gt[b * Mn + 2], pg3 = prob_gt[b * Mn + 3];

    float m0 = cc0, m1 = cc1, m2 = cc2, m3 = cc3;
#pragma unroll
    for (int off = 1; off < 16; off <<= 1) {
      m0 = fminf(m0, __shfl_xor(m0, off));
      m1 = fminf(m1, __shfl_xor(m1, off));
      m2 = fminf(m2, __shfl_xor(m2, off));
      m3 = fminf(m3, __shfl_xor(m3, off));
    }
    int r0 = (m1 < m0) + (m2 < m0) + (m3 < m0);
    int r1 = (m0 <= m1) + (m2 < m1) + (m3 < m1);
    int r2 = (m0 <= m2) + (m1 <= m2) + (m3 < m2);
    int r3 = (m0 <= m3) + (m1 <= m3) + (m2 <= m3);

    float rowsum = 0.f;
    float target = 0.f;
#pragma unroll
    for (int k = 0; k < Mn; ++k) {
      int i = (r0 == k) ? 0 : (r1 == k) ? 1 : (r2 == k) ? 2 : 3;
      float v = (i == 0) ? cc0 : (i == 1) ? cc1 : (i == 2) ? cc2 : cc3;
      float pg = (i == 0) ? pg0 : (i == 1) ? pg1 : (i == 2) ? pg2 : pg3;
      float cap = GAMMA_F - rowsum;
      float excl = 0.f;
#pragma unroll 4
      for (int j = 0; j < Nn; ++j) {
        float vj = __shfl(v, base + j);
        float capj = __shfl(cap, base + j);
        bool pred = (vj < v) || (vj == v && j < n);
        excl += pred ? capj : 0.f;
      }
      float a = fminf(fmaxf(MASS_F - excl, 0.f), cap);
      rowsum += a;
      float p = a * pg * (float)Mn;
      seg_part += p * v;
      target += p;
    }
    kl_part = (target > 0.f)
                  ? target * (logf(target) - logf(prob[tid] + EPS_F))
                  : 0.f;
  }

  // phase 3: global reduction of seg/kl
#pragma unroll
  for (int off = 32; off > 0; off >>= 1) {
    seg_part += __shfl_down(seg_part, off);
    kl_part += __shfl_down(kl_part, off);
  }
  int lane = tid & 63, wv = tid >> 6;
  if (lane == 0) { s_red[wv * 2] = seg_part; s_red[wv * 2 + 1] = kl_part; }
  __syncthreads();
  if (tid == 0) {
    float seg = 0.f, kl = 0.f;
    for (int w = 0; w < 4; ++w) { seg += s_red[w * 2]; kl += s_red[w * 2 + 1]; }
    seg /= (float)Bn;
    kl /= (float)(Bn * Nn);
    out[0] = seg + 1.0f * kl;  // BETA = 1
    out[1] = seg;
    out[2] = kl;
  }
}

extern "C" void kernel_launch(void* const* d_in, const int* in_sizes, int n_in,
                              void* d_out, int out_size, void* d_ws, size_t ws_size,
                              hipStream_t stream) {
  const int* gt = (const int*)d_in[0];          // (B,M,H,W) int32
  const float* sample = (const float*)d_in[1];  // (B,N,C,H,W) f32
  const float* prob = (const float*)d_in[2];    // (B,N)
  const float* prob_gt = (const float*)d_in[3]; // (B,M)
  float* out = (float*)d_out;

  char* ws = (char*)d_ws;
  float* inter_part = (float*)(ws + 0);
  float* ssum_part = (float*)(ws + 131072);
  float* gsum_part = (float*)(ws + 163840);

  inter2_kernel<<<Bn * SEGS, 256, 0, stream>>>(sample, gt, inter_part, ssum_part, gsum_part);
  finish_kernel<<<1, 256, 0, stream>>>(inter_part, ssum_part, gsum_part, prob, prob_gt, out);
}